// Round 6
// baseline (777.471 us; speedup 1.0000x reference)
//
#include <hip/hip_runtime.h>

#define NNODES 100000
#define DIM 128
#define BROWS 256               // rows per bucket
#define NB ((NNODES + BROWS - 1) / BROWS)   // 391 buckets
#define BCAP 5120               // capacity per bucket
#define CHUNK 4096              // edges per pass1 item
#define NBLK 768                // persistent grid: 3 blocks/CU x 256 CU (co-resident)

typedef _Float16 half8 __attribute__((ext_vector_type(8)));
typedef float f32x4 __attribute__((ext_vector_type(4)));
typedef unsigned int u32x4 __attribute__((ext_vector_type(4)));
typedef unsigned long long u64;

__device__ __forceinline__ unsigned int pack_bf16x2(float lo, float hi) {
    unsigned int ul = __float_as_uint(lo);
    unsigned int uh = __float_as_uint(hi);
    ul = (ul + 0x7fffu + ((ul >> 16) & 1u)) >> 16;   // RNE
    uh = (uh + 0x7fffu + ((uh >> 16) & 1u)) & 0xffff0000u;
    return uh | ul;
}

__device__ __forceinline__ void unpack_bf16x8_v(u32x4 v, float* f) {
    f[0] = __uint_as_float(v.x << 16); f[1] = __uint_as_float(v.x & 0xffff0000u);
    f[2] = __uint_as_float(v.y << 16); f[3] = __uint_as_float(v.y & 0xffff0000u);
    f[4] = __uint_as_float(v.z << 16); f[5] = __uint_as_float(v.z & 0xffff0000u);
    f[6] = __uint_as_float(v.w << 16); f[7] = __uint_as_float(v.w & 0xffff0000u);
}

// -------- device-scope grid barrier (persistent grid, all NBLK blocks resident) ----
// release fence -> device-scope signal -> spin -> acquire fence. Handles per-XCD
// L2 non-coherence: threadfence emits L2 writeback/invalidate at agent scope.
__device__ __forceinline__ void gsync(int* bar, int target) {
    __syncthreads();
    if (threadIdx.x == 0) {
        __threadfence();                      // release: flush writes device-wide
        atomicAdd(bar, 1);
        while (atomicAdd(bar, 0) < target) __builtin_amdgcn_s_sleep(4);
        __threadfence();                      // acquire: invalidate stale caches
    }
    __syncthreads();
}

// ---------------- Dense GEMM body via MFMA: Yb(bf16) = A @ W + b ----------------
template <bool IN_BF16>
__device__ __forceinline__ void gemm_body(int blk, const void* __restrict__ Ain,
                                          const _Float16* __restrict__ Wt,
                                          const float* __restrict__ bias,
                                          unsigned short* __restrict__ Yb, int n) {
    const int t = threadIdx.x;
    const int l = t & 63;
    const int lr = l & 15;        // output row within 16-tile
    const int lg = l >> 4;        // 0..3 K-group / output col group
    const int r0 = blk * 128 + (t >> 6) * 32;   // wave owns 32 rows

    half8 xf[2][4];
#pragma unroll
    for (int rt = 0; rt < 2; ++rt) {
        const int row = r0 + rt * 16 + lr;
        const bool ok = row < n;
        if (IN_BF16) {
            const u32x4* __restrict__ A16 = (const u32x4*)Ain;
#pragma unroll
            for (int ks = 0; ks < 4; ++ks) {
                u32x4 v = {0u, 0u, 0u, 0u};
                if (ok) v = A16[(size_t)row * 16 + ks * 4 + lg];
                float f[8];
                unpack_bf16x8_v(v, f);
                half8 h;
#pragma unroll
                for (int j = 0; j < 8; ++j) h[j] = (_Float16)f[j];
                xf[rt][ks] = h;
            }
        } else {
            const f32x4* __restrict__ A4 = (const f32x4*)Ain;
#pragma unroll
            for (int ks = 0; ks < 4; ++ks) {
                f32x4 v0 = {0.f, 0.f, 0.f, 0.f};
                f32x4 v1 = v0;
                if (ok) {
                    v0 = A4[(size_t)row * 32 + ks * 8 + lg * 2];
                    v1 = A4[(size_t)row * 32 + ks * 8 + lg * 2 + 1];
                }
                half8 h;
                h[0] = (_Float16)v0.x; h[1] = (_Float16)v0.y;
                h[2] = (_Float16)v0.z; h[3] = (_Float16)v0.w;
                h[4] = (_Float16)v1.x; h[5] = (_Float16)v1.y;
                h[6] = (_Float16)v1.z; h[7] = (_Float16)v1.w;
                xf[rt][ks] = h;
            }
        }
    }

    const f32x4 zero4 = {0.f, 0.f, 0.f, 0.f};
    f32x4 acc[2][8];
#pragma unroll
    for (int rt = 0; rt < 2; ++rt)
#pragma unroll
        for (int ct = 0; ct < 8; ++ct) acc[rt][ct] = zero4;

    const half8* __restrict__ Wf = (const half8*)Wt;   // 16 half8 per Wt row
#pragma unroll
    for (int ct = 0; ct < 8; ++ct) {
        half8 wf[4];
#pragma unroll
        for (int ks = 0; ks < 4; ++ks)
            wf[ks] = Wf[(ct * 16 + lr) * 16 + ks * 4 + lg];
#pragma unroll
        for (int ks = 0; ks < 4; ++ks) {
            acc[0][ct] = __builtin_amdgcn_mfma_f32_16x16x32_f16(wf[ks], xf[0][ks], acc[0][ct], 0, 0, 0);
            acc[1][ct] = __builtin_amdgcn_mfma_f32_16x16x32_f16(wf[ks], xf[1][ks], acc[1][ct], 0, 0, 0);
        }
    }

#pragma unroll
    for (int ct = 0; ct < 8; ++ct) {
        const int c0 = ct * 16 + lg * 4;
        const float4 bv = *(const float4*)&bias[c0];
#pragma unroll
        for (int rt = 0; rt < 2; ++rt) {
            const int row = r0 + rt * 16 + lr;
            if (row < n) {
                f32x4 a = acc[rt][ct];
                const uint2 pv = make_uint2(pack_bf16x2(a[0] + bv.x, a[1] + bv.y),
                                            pack_bf16x2(a[2] + bv.z, a[3] + bv.w));
                *(uint2*)&Yb[(size_t)row * DIM + c0] = pv;
            }
        }
    }
}

// ---------------- W prep item: fp32 W[k][c] -> f16 Wt[c][k] ----------------
__device__ __forceinline__ void prep_w_item(int b, const float* __restrict__ W1s,
                                            const float* __restrict__ W2s,
                                            _Float16* __restrict__ Wt1,
                                            _Float16* __restrict__ Wt2) {
    const float* __restrict__ W = (b & 4) ? W2s : W1s;
    _Float16* __restrict__ Wt = (b & 4) ? Wt2 : Wt1;
    const int base = (b & 3) * 4096;
    for (int i = threadIdx.x; i < 4096; i += 256) {
        const int e = base + i;
        Wt[(e & 127) * 128 + (e >> 7)] = (_Float16)W[e];
    }
}

// ---------------- pass1 item: bin CHUNK edges into row-buckets ----------------
__device__ __forceinline__ void pass1_chunk(int c, const int* __restrict__ rows,
                                            const int* __restrict__ cols,
                                            const float* __restrict__ vals,
                                            int* __restrict__ bcnt,
                                            int2* __restrict__ tmp, int nnz,
                                            int* hist, int* base, int* cur) {
    const int t = threadIdx.x;
    const int e0 = c * CHUNK;
    const int e1 = min(e0 + CHUNK, nnz);

    for (int i = t; i < NB; i += 256) { hist[i] = 0; cur[i] = 0; }
    __syncthreads();

    for (int i = e0 + t; i < e1; i += 256)
        atomicAdd(&hist[rows[i] >> 8], 1);
    __syncthreads();

    for (int i = t; i < NB; i += 256)
        base[i] = (hist[i] > 0) ? atomicAdd(&bcnt[i], hist[i]) : 0;
    __syncthreads();

    for (int i = e0 + t; i < e1; i += 256) {
        const int r = rows[i];
        const int b = r >> 8;
        const int pos = base[b] + atomicAdd(&cur[b], 1);
        if (pos < BCAP)
            tmp[(size_t)b * BCAP + pos] =
                make_int2(((r & 255) << 24) | cols[i], __float_as_int(vals[i]));
    }
    __syncthreads();
}

// ---------------- pass2 item: finalize one bucket's CSR window ----------------
__device__ __forceinline__ void pass2_bucket(int b, const int2* __restrict__ tmp,
                                             const int* __restrict__ bcnt,
                                             int2* __restrict__ epack,
                                             int* __restrict__ row_ptr,
                                             int* __restrict__ counts, int n,
                                             int* cnt, int* s, int* cur) {
    const int t = threadIdx.x;
    const int row0 = b * BROWS;
    const int nrows = min(BROWS, n - row0);
    const int m = min(bcnt[b], BCAP);
    const int2* __restrict__ src = tmp + (size_t)b * BCAP;

    // base = exclusive prefix sum of bcnt[0..b)
    int partial = 0;
    for (int i = t; i < b; i += 256) partial += bcnt[i];
    s[t] = partial;
    __syncthreads();
    for (int off = 128; off >= 1; off >>= 1) {
        if (t < off) s[t] += s[t + off];
        __syncthreads();
    }
    const int base = s[0];
    __syncthreads();

    cnt[t] = 0;
    __syncthreads();
    for (int i = t; i < m; i += 256)
        atomicAdd(&cnt[((unsigned)src[i].x) >> 24], 1);
    __syncthreads();

    const int v = cnt[t];
    s[t] = v;
    __syncthreads();
    for (int off = 1; off < 256; off <<= 1) {
        int x = (t >= off) ? s[t - off] : 0;
        __syncthreads();
        s[t] += x;
        __syncthreads();
    }
    const int excl = s[t] - v;
    if (t < nrows) {
        row_ptr[row0 + t] = base + excl;
        counts[row0 + t] = v;
    }
    cur[t] = base + excl;
    __syncthreads();

    for (int i = t; i < m; i += 256) {
        const int2 e = src[i];
        const int rl = ((unsigned)e.x) >> 24;
        const int pos = atomicAdd(&cur[rl], 1);
        epack[pos] = make_int2(e.x & 0xFFFFFF, e.y);
    }
    __syncthreads();
}

// ---------------- SpMM item: 16 rows, 16 lanes/row, deep 8-edge unroll ----------
template <bool RELU_OUT, bool OUT_BF16>
__device__ __forceinline__ void spmm_item(int g, const int* __restrict__ row_ptr,
                                          const int* __restrict__ counts,
                                          const int2* __restrict__ epack,
                                          const unsigned short* __restrict__ Xb,
                                          void* __restrict__ out, int n) {
    const int t = threadIdx.x;
    const int r = g * 16 + (t >> 4);
    const int lane = t & 15;
    if (r >= n) return;
    const int start = row_ptr[r];
    const int cnt = counts[r];
    const u32x4* __restrict__ X16 = (const u32x4*)Xb;
    const u64* __restrict__ ep = (const u64*)(epack + start);

    float acc[8];
#pragma unroll
    for (int k = 0; k < 8; ++k) acc[k] = 0.f;

    int j = 0;
    for (; j + 8 <= cnt; j += 8) {
        u64 e[8];
#pragma unroll
        for (int q = 0; q < 8; ++q) e[q] = ep[j + q];
        u32x4 x[8];
#pragma unroll
        for (int q = 0; q < 8; ++q)
            x[q] = X16[(size_t)(unsigned)(e[q] & 0xffffffffu) * 16 + lane];
#pragma unroll
        for (int q = 0; q < 8; ++q) {
            const float v = __uint_as_float((unsigned)(e[q] >> 32));
            float f[8];
            unpack_bf16x8_v(x[q], f);
#pragma unroll
            for (int k = 0; k < 8; ++k) acc[k] = fmaf(v, f[k], acc[k]);
        }
    }
    for (; j + 2 <= cnt; j += 2) {
        const u64 e0 = ep[j], e1 = ep[j + 1];
        const u32x4 x0 = X16[(size_t)(unsigned)(e0 & 0xffffffffu) * 16 + lane];
        const u32x4 x1 = X16[(size_t)(unsigned)(e1 & 0xffffffffu) * 16 + lane];
        const float v0 = __uint_as_float((unsigned)(e0 >> 32));
        const float v1 = __uint_as_float((unsigned)(e1 >> 32));
        float f0[8], f1[8];
        unpack_bf16x8_v(x0, f0); unpack_bf16x8_v(x1, f1);
#pragma unroll
        for (int k = 0; k < 8; ++k)
            acc[k] += v0 * f0[k] + v1 * f1[k];
    }
    if (j < cnt) {
        const u64 e = ep[j];
        const u32x4 x = X16[(size_t)(unsigned)(e & 0xffffffffu) * 16 + lane];
        const float v = __uint_as_float((unsigned)(e >> 32));
        float f[8];
        unpack_bf16x8_v(x, f);
#pragma unroll
        for (int k = 0; k < 8; ++k) acc[k] = fmaf(v, f[k], acc[k]);
    }

    if (RELU_OUT) {
#pragma unroll
        for (int k = 0; k < 8; ++k) acc[k] = fmaxf(acc[k], 0.f);
    }

    if (OUT_BF16) {
        u32x4 pv;
        pv.x = pack_bf16x2(acc[0], acc[1]); pv.y = pack_bf16x2(acc[2], acc[3]);
        pv.z = pack_bf16x2(acc[4], acc[5]); pv.w = pack_bf16x2(acc[6], acc[7]);
        ((u32x4*)out)[(size_t)r * 16 + lane] = pv;        // re-read by gemm2
    } else {
        float* of = (float*)out;
        f32x4 a0 = {acc[0], acc[1], acc[2], acc[3]};
        f32x4 a1 = {acc[4], acc[5], acc[6], acc[7]};
        __builtin_nontemporal_store(a0, (f32x4*)&of[(size_t)r * DIM + lane * 8]);
        __builtin_nontemporal_store(a1, (f32x4*)&of[(size_t)r * DIM + lane * 8 + 4]);
    }
}

// ---------------- the single persistent mega-kernel ----------------
// Phases (grid-strided over NBLK blocks, device-scope barrier between):
//   A: pass1 binning + W prep | B: pass2 CSR finalize + gemm1 | C: spmm1
//   D: gemm2                  | E: spmm2
__global__ __launch_bounds__(256, 3) void mega(
    const int* __restrict__ Hrows, const int* __restrict__ Hcols,
    const float* __restrict__ Hvals, const float* __restrict__ X,
    const float* __restrict__ W1, const float* __restrict__ b1,
    const float* __restrict__ W2, const float* __restrict__ b2,
    _Float16* __restrict__ Wt1, _Float16* __restrict__ Wt2,
    int* __restrict__ bcnt, int* __restrict__ bar,
    int2* __restrict__ tmp, int2* __restrict__ epack,
    int* __restrict__ row_ptr, int* __restrict__ counts,
    unsigned short* __restrict__ Yb, unsigned short* __restrict__ hb,
    float* __restrict__ out, int nnz, int n) {
    __shared__ int sh0[NB];
    __shared__ int sh1[NB];
    __shared__ int sh2[NB];

    const int bid = blockIdx.x;
    const int p1c = (nnz + CHUNK - 1) / CHUNK;
    const int gt = (n + 127) >> 7;
    const int spi = (n + 15) >> 4;

    // ---- phase A: pass1 binning (p1c items) + W prep (8 items) ----
    for (int i = bid; i < p1c + 8; i += NBLK) {
        if (i < p1c) pass1_chunk(i, Hrows, Hcols, Hvals, bcnt, tmp, nnz, sh0, sh1, sh2);
        else         prep_w_item(i - p1c, W1, W2, Wt1, Wt2);
    }
    gsync(bar, NBLK);

    // ---- phase B: pass2 CSR finalize (NB items) + gemm1 (gt items) ----
    for (int i = bid; i < NB + gt; i += NBLK) {
        if (i < NB) pass2_bucket(i, tmp, bcnt, epack, row_ptr, counts, n, sh0, sh1, sh2);
        else        gemm_body<false>(i - NB, X, Wt1, b1, Yb, n);
    }
    gsync(bar, 2 * NBLK);

    // ---- phase C: spmm1  hb = relu(H @ Yb) (bf16) ----
    for (int i = bid; i < spi; i += NBLK)
        spmm_item<true, true>(i, row_ptr, counts, epack, Yb, hb, n);
    gsync(bar, 3 * NBLK);

    // ---- phase D: gemm2  Yb = hb @ W2 + b2 (bf16) ----
    for (int i = bid; i < gt; i += NBLK)
        gemm_body<true>(i, hb, Wt2, b2, Yb, n);
    gsync(bar, 4 * NBLK);

    // ---- phase E: spmm2  out = H @ Yb (fp32) ----
    for (int i = bid; i < spi; i += NBLK)
        spmm_item<false, false>(i, row_ptr, counts, epack, Yb, out, n);
}

extern "C" void kernel_launch(void* const* d_in, const int* in_sizes, int n_in,
                              void* d_out, int out_size, void* d_ws, size_t ws_size,
                              hipStream_t stream) {
    const float* X      = (const float*)d_in[0];
    const int*   H_rows = (const int*)d_in[1];
    const int*   H_cols = (const int*)d_in[2];
    const float* H_vals = (const float*)d_in[3];
    const float* W1     = (const float*)d_in[4];
    const float* b1     = (const float*)d_in[5];
    const float* W2     = (const float*)d_in[6];
    const float* b2     = (const float*)d_in[7];
    float* out = (float*)d_out;

    const int E = in_sizes[1];
    const int N = NNODES;
    const size_t bmat_bytes = (size_t)N * DIM * 2;

    // Workspace layout (~81 MB + 64KB)
    char* p = (char*)d_ws;
    unsigned short* Yb = (unsigned short*)p;  p += bmat_bytes;              // 25.6 MB
    unsigned short* hb = (unsigned short*)p;  p += bmat_bytes;              // 25.6 MB
    _Float16* Wt1      = (_Float16*)p;        p += 128 * 128 * 2;           // 32 KB
    _Float16* Wt2      = (_Float16*)p;        p += 128 * 128 * 2;           // 32 KB
    int2* epack        = (int2*)p;            p += (size_t)E * 8;           // 12.8 MB
    int2* tmp          = (int2*)p;            p += (size_t)NB * BCAP * 8;   // 16.0 MB
    int*  bcnt         = (int*)p;             p += (size_t)NB * 4;
    int*  bar          = (int*)p;             p += 16 * 4;                  // barrier counter
    int*  row_ptr      = (int*)p;             p += (size_t)N * 4;
    int*  counts       = (int*)p;             p += (size_t)N * 4;

    // zero bucket counts + barrier counter (one memset), then the single kernel
    hipMemsetAsync(bcnt, 0, (size_t)(NB + 16) * 4, stream);
    mega<<<NBLK, 256, 0, stream>>>(H_rows, H_cols, H_vals, X, W1, b1, W2, b2,
                                   Wt1, Wt2, bcnt, bar, tmp, epack,
                                   row_ptr, counts, Yb, hb, out, E, N);
}

// Round 7
// 340.107 us; speedup vs baseline: 2.2860x; 2.2860x over previous
//
#include <hip/hip_runtime.h>

#define NNODES 100000
#define DIM 128
#define BROWS 256               // rows per bucket
#define NB ((NNODES + BROWS - 1) / BROWS)   // 391 buckets
#define BCAP 5120               // capacity per bucket
#define CHUNK 4096              // edges per pass1 block

typedef _Float16 half8 __attribute__((ext_vector_type(8)));
typedef float f32x4 __attribute__((ext_vector_type(4)));
typedef unsigned int u32x4 __attribute__((ext_vector_type(4)));
typedef unsigned long long u64;

__device__ __forceinline__ unsigned int pack_bf16x2(float lo, float hi) {
    unsigned int ul = __float_as_uint(lo);
    unsigned int uh = __float_as_uint(hi);
    ul = (ul + 0x7fffu + ((ul >> 16) & 1u)) >> 16;   // RNE
    uh = (uh + 0x7fffu + ((uh >> 16) & 1u)) & 0xffff0000u;
    return uh | ul;
}

__device__ __forceinline__ void unpack_bf16x8_v(u32x4 v, float* f) {
    f[0] = __uint_as_float(v.x << 16); f[1] = __uint_as_float(v.x & 0xffff0000u);
    f[2] = __uint_as_float(v.y << 16); f[3] = __uint_as_float(v.y & 0xffff0000u);
    f[4] = __uint_as_float(v.z << 16); f[5] = __uint_as_float(v.z & 0xffff0000u);
    f[6] = __uint_as_float(v.w << 16); f[7] = __uint_as_float(v.w & 0xffff0000u);
}

// ---------------- Dense GEMM body via MFMA: Yb(bf16) = A @ W + b ----------------
// Swapped-operand mfma: D = (W^T tile) x (X tile); lane's 4 acc regs are 4
// consecutive output columns of one row -> contiguous uint2 bf16 stores.
template <bool IN_BF16>
__device__ __forceinline__ void gemm_body(int blk, const void* __restrict__ Ain,
                                          const _Float16* __restrict__ Wt,
                                          const float* __restrict__ bias,
                                          unsigned short* __restrict__ Yb, int n) {
    const int t = threadIdx.x;
    const int l = t & 63;
    const int lr = l & 15;        // output row within 16-tile
    const int lg = l >> 4;        // 0..3 K-group / output col group
    const int r0 = blk * 128 + (t >> 6) * 32;   // wave owns 32 rows

    half8 xf[2][4];
#pragma unroll
    for (int rt = 0; rt < 2; ++rt) {
        const int row = r0 + rt * 16 + lr;
        const bool ok = row < n;
        if (IN_BF16) {
            const u32x4* __restrict__ A16 = (const u32x4*)Ain;
#pragma unroll
            for (int ks = 0; ks < 4; ++ks) {
                u32x4 v = {0u, 0u, 0u, 0u};
                if (ok) v = A16[(size_t)row * 16 + ks * 4 + lg];
                float f[8];
                unpack_bf16x8_v(v, f);
                half8 h;
#pragma unroll
                for (int j = 0; j < 8; ++j) h[j] = (_Float16)f[j];
                xf[rt][ks] = h;
            }
        } else {
            const f32x4* __restrict__ A4 = (const f32x4*)Ain;
#pragma unroll
            for (int ks = 0; ks < 4; ++ks) {
                f32x4 v0 = {0.f, 0.f, 0.f, 0.f};
                f32x4 v1 = v0;
                if (ok) {
                    v0 = A4[(size_t)row * 32 + ks * 8 + lg * 2];
                    v1 = A4[(size_t)row * 32 + ks * 8 + lg * 2 + 1];
                }
                half8 h;
                h[0] = (_Float16)v0.x; h[1] = (_Float16)v0.y;
                h[2] = (_Float16)v0.z; h[3] = (_Float16)v0.w;
                h[4] = (_Float16)v1.x; h[5] = (_Float16)v1.y;
                h[6] = (_Float16)v1.z; h[7] = (_Float16)v1.w;
                xf[rt][ks] = h;
            }
        }
    }

    const f32x4 zero4 = {0.f, 0.f, 0.f, 0.f};
    f32x4 acc[2][8];
#pragma unroll
    for (int rt = 0; rt < 2; ++rt)
#pragma unroll
        for (int ct = 0; ct < 8; ++ct) acc[rt][ct] = zero4;

    const half8* __restrict__ Wf = (const half8*)Wt;   // 16 half8 per Wt row
#pragma unroll
    for (int ct = 0; ct < 8; ++ct) {
        half8 wf[4];
#pragma unroll
        for (int ks = 0; ks < 4; ++ks)
            wf[ks] = Wf[(ct * 16 + lr) * 16 + ks * 4 + lg];
#pragma unroll
        for (int ks = 0; ks < 4; ++ks) {
            acc[0][ct] = __builtin_amdgcn_mfma_f32_16x16x32_f16(wf[ks], xf[0][ks], acc[0][ct], 0, 0, 0);
            acc[1][ct] = __builtin_amdgcn_mfma_f32_16x16x32_f16(wf[ks], xf[1][ks], acc[1][ct], 0, 0, 0);
        }
    }

#pragma unroll
    for (int ct = 0; ct < 8; ++ct) {
        const int c0 = ct * 16 + lg * 4;
        const float4 bv = *(const float4*)&bias[c0];
#pragma unroll
        for (int rt = 0; rt < 2; ++rt) {
            const int row = r0 + rt * 16 + lr;
            if (row < n) {
                f32x4 a = acc[rt][ct];
                const uint2 pv = make_uint2(pack_bf16x2(a[0] + bv.x, a[1] + bv.y),
                                            pack_bf16x2(a[2] + bv.z, a[3] + bv.w));
                *(uint2*)&Yb[(size_t)row * DIM + c0] = pv;
            }
        }
    }
}

// ---------------- pass1 + W-prep (fused grids) ----------------
__global__ __launch_bounds__(256) void pass1_bin(const int* __restrict__ rows,
                                                 const int* __restrict__ cols,
                                                 const float* __restrict__ vals,
                                                 int* __restrict__ bcnt,
                                                 int2* __restrict__ tmp, int nnz,
                                                 int p1_blocks,
                                                 const float* __restrict__ W1s,
                                                 const float* __restrict__ W2s,
                                                 _Float16* __restrict__ Wt1,
                                                 _Float16* __restrict__ Wt2) {
    __shared__ int hist[NB];
    __shared__ int base[NB];
    __shared__ int cur[NB];
    const int t = threadIdx.x;

    if (blockIdx.x >= (unsigned)p1_blocks) {        // ---- W prep blocks (8) ----
        const int b = blockIdx.x - p1_blocks;       // 0..7
        const float* __restrict__ W = (b & 4) ? W2s : W1s;
        _Float16* __restrict__ Wt = (b & 4) ? Wt2 : Wt1;
        const int base2 = (b & 3) * 4096;
        for (int i = t; i < 4096; i += 256) {
            const int e = base2 + i;
            const int k = e >> 7, c = e & 127;
            Wt[c * 128 + k] = (_Float16)W[e];
        }
        return;
    }

    const int e0 = blockIdx.x * CHUNK;
    const int e1 = min(e0 + CHUNK, nnz);

    for (int i = t; i < NB; i += 256) { hist[i] = 0; cur[i] = 0; }
    __syncthreads();

    for (int i = e0 + t; i < e1; i += 256)
        atomicAdd(&hist[rows[i] >> 8], 1);
    __syncthreads();

    for (int i = t; i < NB; i += 256)
        base[i] = (hist[i] > 0) ? atomicAdd(&bcnt[i], hist[i]) : 0;
    __syncthreads();

    for (int i = e0 + t; i < e1; i += 256) {
        const int r = rows[i];
        const int b = r >> 8;
        const int pos = base[b] + atomicAdd(&cur[b], 1);
        if (pos < BCAP)
            tmp[(size_t)b * BCAP + pos] =
                make_int2(((r & 255) << 24) | cols[i], __float_as_int(vals[i]));
    }
}

// ---------------- fused pass2 (CSR finalize) + gemm layer 1 ----------------
__global__ __launch_bounds__(256) void pass2_gemm1(const int2* __restrict__ tmp,
                                                   const int* __restrict__ bcnt,
                                                   int2* __restrict__ epack,
                                                   int* __restrict__ row_ptr,
                                                   int* __restrict__ counts,
                                                   const float* __restrict__ X,
                                                   const _Float16* __restrict__ Wt1,
                                                   const float* __restrict__ b1,
                                                   unsigned short* __restrict__ Yb, int n) {
    __shared__ int cnt[256];
    __shared__ int s[256];
    __shared__ int cur[256];

    if (blockIdx.x >= NB) {                          // ---- gemm layer-1 blocks ----
        gemm_body<false>(blockIdx.x - NB, X, Wt1, b1, Yb, n);
        return;
    }

    const int b = blockIdx.x;
    const int t = threadIdx.x;
    const int row0 = b * BROWS;
    const int nrows = min(BROWS, n - row0);
    const int m = min(bcnt[b], BCAP);
    const int2* __restrict__ src = tmp + (size_t)b * BCAP;

    // base = exclusive prefix sum of bcnt[0..b)  (L2-hot ints)
    int partial = 0;
    for (int i = t; i < b; i += 256) partial += bcnt[i];
    s[t] = partial;
    __syncthreads();
    for (int off = 128; off >= 1; off >>= 1) {
        if (t < off) s[t] += s[t + off];
        __syncthreads();
    }
    const int base = s[0];
    __syncthreads();

    cnt[t] = 0;
    __syncthreads();
    for (int i = t; i < m; i += 256)
        atomicAdd(&cnt[((unsigned)src[i].x) >> 24], 1);
    __syncthreads();

    const int v = cnt[t];
    s[t] = v;
    __syncthreads();
    for (int off = 1; off < 256; off <<= 1) {
        int x = (t >= off) ? s[t - off] : 0;
        __syncthreads();
        s[t] += x;
        __syncthreads();
    }
    const int excl = s[t] - v;
    if (t < nrows) {
        row_ptr[row0 + t] = base + excl;
        counts[row0 + t] = v;
    }
    cur[t] = base + excl;
    __syncthreads();

    for (int i = t; i < m; i += 256) {
        const int2 e = src[i];
        const int rl = ((unsigned)e.x) >> 24;
        const int pos = atomicAdd(&cur[rl], 1);
        epack[pos] = make_int2(e.x & 0xFFFFFF, e.y);
    }
}

// ------------- fused SpMM + GEMM: Yb2 = relu(H @ Yb) @ W2 + b2  (all in-block) ----
// Block = 16 rows x 16 lanes. Phase 1: CSR gather spmm (round-5 deep unroll) ->
// relu -> f16 row staged in LDS (padded stride 136: conflict-free frag reads).
// Phase 2: one barrier; 4 waves x (2 col-tiles x 4 K-steps) MFMA vs L2-hot Wt2;
// bias + bf16 pack + coalesced store. Deletes the hb round-trip AND the whole
// gemm2 dispatch.
__global__ __launch_bounds__(256) void spmm1_gemm2(const int* __restrict__ row_ptr,
                                                   const int* __restrict__ counts,
                                                   const int2* __restrict__ epack,
                                                   const unsigned short* __restrict__ Xb,
                                                   const _Float16* __restrict__ Wt2,
                                                   const float* __restrict__ bias,
                                                   unsigned short* __restrict__ Yb2, int n) {
    __shared__ _Float16 hl[16][136];
    const int t = threadIdx.x;
    const int rloc = t >> 4;
    const int lane = t & 15;
    const int r = blockIdx.x * 16 + rloc;
    const bool valid = r < n;

    float acc[8];
#pragma unroll
    for (int k = 0; k < 8; ++k) acc[k] = 0.f;

    if (valid) {
        const int start = row_ptr[r];
        const int cnt = counts[r];
        const u32x4* __restrict__ X16 = (const u32x4*)Xb;
        const u64* __restrict__ ep = (const u64*)(epack + start);

        int j = 0;
        for (; j + 8 <= cnt; j += 8) {
            u64 e[8];
#pragma unroll
            for (int q = 0; q < 8; ++q) e[q] = ep[j + q];
            u32x4 x[8];
#pragma unroll
            for (int q = 0; q < 8; ++q)
                x[q] = X16[(size_t)(unsigned)(e[q] & 0xffffffffu) * 16 + lane];
#pragma unroll
            for (int q = 0; q < 8; ++q) {
                const float v = __uint_as_float((unsigned)(e[q] >> 32));
                float f[8];
                unpack_bf16x8_v(x[q], f);
#pragma unroll
                for (int k = 0; k < 8; ++k) acc[k] = fmaf(v, f[k], acc[k]);
            }
        }
        for (; j + 2 <= cnt; j += 2) {
            const u64 e0 = ep[j], e1 = ep[j + 1];
            const u32x4 x0 = X16[(size_t)(unsigned)(e0 & 0xffffffffu) * 16 + lane];
            const u32x4 x1 = X16[(size_t)(unsigned)(e1 & 0xffffffffu) * 16 + lane];
            const float v0 = __uint_as_float((unsigned)(e0 >> 32));
            const float v1 = __uint_as_float((unsigned)(e1 >> 32));
            float f0[8], f1[8];
            unpack_bf16x8_v(x0, f0); unpack_bf16x8_v(x1, f1);
#pragma unroll
            for (int k = 0; k < 8; ++k)
                acc[k] += v0 * f0[k] + v1 * f1[k];
        }
        if (j < cnt) {
            const u64 e = ep[j];
            const u32x4 x = X16[(size_t)(unsigned)(e & 0xffffffffu) * 16 + lane];
            const float v = __uint_as_float((unsigned)(e >> 32));
            float f[8];
            unpack_bf16x8_v(x, f);
#pragma unroll
            for (int k = 0; k < 8; ++k) acc[k] = fmaf(v, f[k], acc[k]);
        }
    }

    // relu -> f16 -> LDS  (h row = relu(spmm row); gemm2 consumed it as f16 anyway)
    {
        half8 h;
#pragma unroll
        for (int k = 0; k < 8; ++k) h[k] = (_Float16)fmaxf(acc[k], 0.f);
        *(half8*)&hl[rloc][lane * 8] = h;
    }
    __syncthreads();

    // ---- gemm phase: wave w handles col-tiles {2w, 2w+1} ----
    const int l = t & 63;
    const int lr = l & 15;
    const int lg = l >> 4;
    const int w = t >> 6;

    half8 hf[4];
#pragma unroll
    for (int ks = 0; ks < 4; ++ks)
        hf[ks] = *(const half8*)&hl[lr][ks * 32 + lg * 8];

    const half8* __restrict__ Wf = (const half8*)Wt2;   // 16 half8 per Wt row
    const f32x4 zero4 = {0.f, 0.f, 0.f, 0.f};
#pragma unroll
    for (int ct2 = 0; ct2 < 2; ++ct2) {
        const int ct = w * 2 + ct2;
        f32x4 a2 = zero4;
#pragma unroll
        for (int ks = 0; ks < 4; ++ks) {
            const half8 wf = Wf[(ct * 16 + lr) * 16 + ks * 4 + lg];
            a2 = __builtin_amdgcn_mfma_f32_16x16x32_f16(wf, hf[ks], a2, 0, 0, 0);
        }
        const int c0 = ct * 16 + lg * 4;
        const float4 bv = *(const float4*)&bias[c0];
        const int row = blockIdx.x * 16 + lr;
        if (row < n) {
            const uint2 pv = make_uint2(pack_bf16x2(a2[0] + bv.x, a2[1] + bv.y),
                                        pack_bf16x2(a2[2] + bv.z, a2[3] + bv.w));
            *(uint2*)&Yb2[(size_t)row * DIM + c0] = pv;
        }
    }
}

// ---------------- SpMM layer 2: out = H @ Yb2  (fp32 out) ----------------
__global__ __launch_bounds__(256) void spmm_csr(const int* __restrict__ row_ptr,
                                                const int* __restrict__ counts,
                                                const int2* __restrict__ epack,
                                                const unsigned short* __restrict__ Xb,
                                                float* __restrict__ out, int n) {
    const int gid = blockIdx.x * blockDim.x + threadIdx.x;
    const int r = gid >> 4;
    const int lane = gid & 15;
    if (r >= n) return;
    const int start = row_ptr[r];
    const int cnt = counts[r];
    const u32x4* __restrict__ X16 = (const u32x4*)Xb;
    const u64* __restrict__ ep = (const u64*)(epack + start);

    float acc[8];
#pragma unroll
    for (int k = 0; k < 8; ++k) acc[k] = 0.f;

    int j = 0;
    for (; j + 8 <= cnt; j += 8) {
        u64 e[8];
#pragma unroll
        for (int q = 0; q < 8; ++q) e[q] = ep[j + q];
        u32x4 x[8];
#pragma unroll
        for (int q = 0; q < 8; ++q)
            x[q] = X16[(size_t)(unsigned)(e[q] & 0xffffffffu) * 16 + lane];
#pragma unroll
        for (int q = 0; q < 8; ++q) {
            const float v = __uint_as_float((unsigned)(e[q] >> 32));
            float f[8];
            unpack_bf16x8_v(x[q], f);
#pragma unroll
            for (int k = 0; k < 8; ++k) acc[k] = fmaf(v, f[k], acc[k]);
        }
    }
    for (; j + 2 <= cnt; j += 2) {
        const u64 e0 = ep[j], e1 = ep[j + 1];
        const u32x4 x0 = X16[(size_t)(unsigned)(e0 & 0xffffffffu) * 16 + lane];
        const u32x4 x1 = X16[(size_t)(unsigned)(e1 & 0xffffffffu) * 16 + lane];
        const float v0 = __uint_as_float((unsigned)(e0 >> 32));
        const float v1 = __uint_as_float((unsigned)(e1 >> 32));
        float f0[8], f1[8];
        unpack_bf16x8_v(x0, f0); unpack_bf16x8_v(x1, f1);
#pragma unroll
        for (int k = 0; k < 8; ++k)
            acc[k] += v0 * f0[k] + v1 * f1[k];
    }
    if (j < cnt) {
        const u64 e = ep[j];
        const u32x4 x = X16[(size_t)(unsigned)(e & 0xffffffffu) * 16 + lane];
        const float v = __uint_as_float((unsigned)(e >> 32));
        float f[8];
        unpack_bf16x8_v(x, f);
#pragma unroll
        for (int k = 0; k < 8; ++k) acc[k] = fmaf(v, f[k], acc[k]);
    }

    f32x4 a0 = {acc[0], acc[1], acc[2], acc[3]};
    f32x4 a1 = {acc[4], acc[5], acc[6], acc[7]};
    __builtin_nontemporal_store(a0, (f32x4*)&out[(size_t)r * DIM + lane * 8]);
    __builtin_nontemporal_store(a1, (f32x4*)&out[(size_t)r * DIM + lane * 8 + 4]);
}

extern "C" void kernel_launch(void* const* d_in, const int* in_sizes, int n_in,
                              void* d_out, int out_size, void* d_ws, size_t ws_size,
                              hipStream_t stream) {
    const float* X      = (const float*)d_in[0];
    const int*   H_rows = (const int*)d_in[1];
    const int*   H_cols = (const int*)d_in[2];
    const float* H_vals = (const float*)d_in[3];
    const float* W1     = (const float*)d_in[4];
    const float* b1     = (const float*)d_in[5];
    const float* W2     = (const float*)d_in[6];
    const float* b2     = (const float*)d_in[7];
    float* out = (float*)d_out;

    const int E = in_sizes[1];
    const int N = NNODES;
    const size_t bmat_bytes = (size_t)N * DIM * 2;

    const int gemm_blocks = (N + 127) / 128;
    const int p1_blocks = (E + CHUNK - 1) / CHUNK;
    const int fused_blocks = (N + 15) / 16;
    const int spmm_blocks = (N * 16 + 255) / 256;

    // Workspace layout (~81 MB + 64KB)
    char* p = (char*)d_ws;
    unsigned short* Yb  = (unsigned short*)p; p += bmat_bytes;              // 25.6 MB
    unsigned short* Yb2 = (unsigned short*)p; p += bmat_bytes;              // 25.6 MB
    _Float16* Wt1      = (_Float16*)p;        p += 128 * 128 * 2;           // 32 KB
    _Float16* Wt2      = (_Float16*)p;        p += 128 * 128 * 2;           // 32 KB
    int2* epack        = (int2*)p;            p += (size_t)E * 8;           // 12.8 MB
    int2* tmp          = (int2*)p;            p += (size_t)NB * BCAP * 8;   // 16.0 MB
    int*  bcnt         = (int*)p;             p += (size_t)NB * 4;
    int*  row_ptr      = (int*)p;             p += (size_t)N * 4;
    int*  counts       = (int*)p;             p += (size_t)N * 4;

    // ---- pass1 binning + W prep (fused grids) ----
    hipMemsetAsync(bcnt, 0, (size_t)NB * 4, stream);
    pass1_bin<<<p1_blocks + 8, 256, 0, stream>>>(H_rows, H_cols, H_vals, bcnt, tmp, E,
                                                 p1_blocks, W1, W2, Wt1, Wt2);

    // ---- fused: CSR finalize (391 blocks) + layer-1 GEMM (782 blocks) ----
    pass2_gemm1<<<NB + gemm_blocks, 256, 0, stream>>>(tmp, bcnt, epack, row_ptr, counts,
                                                      X, Wt1, b1, Yb, N);

    // ---- fused: spmm1 + relu + gemm2  (Yb2 = relu(H@Yb) @ W2 + b2) ----
    spmm1_gemm2<<<fused_blocks, 256, 0, stream>>>(row_ptr, counts, epack, Yb, Wt2, b2, Yb2, N);

    // ---- spmm2: out = H @ Yb2 (fp32) ----
    spmm_csr<<<spmm_blocks, 256, 0, stream>>>(row_ptr, counts, epack, Yb2, out, N);
}